// Round 1
// baseline (238.775 us; speedup 1.0000x reference)
//
#include <hip/hip_runtime.h>

typedef unsigned int u32;
typedef unsigned short u16;
typedef __attribute__((ext_vector_type(8))) __bf16 bf16x8;
typedef __attribute__((ext_vector_type(4))) float f32x4;

#define NB 16384
#define NM 4096
#define ND 512
#define NOUT 128

// ---------- helpers ----------
__device__ __forceinline__ u16 f2bf(float f) {
  u32 u = __float_as_uint(f);
  u += 0x7FFFu + ((u >> 16) & 1u);   // RNE
  return (u16)(u >> 16);
}

__device__ __forceinline__ void stage16(const u16* g, u16* l) {
  // async global->LDS, 16B per lane; HW uses lane0's LDS addr as wave base + lane*16
  __builtin_amdgcn_global_load_lds((__attribute__((address_space(1))) void*)g,
                                   (__attribute__((address_space(3))) void*)l,
                                   16, 0, 0);
}

// ---------- prep: x -> bf16 swizzled [rb(128)][kg(64)][row(128)][8], x2, zero s2 ----------
__global__ __launch_bounds__(256) void prep_x(const float* __restrict__ x,
                                              u16* __restrict__ x_ws,
                                              float* __restrict__ x2,
                                              float* __restrict__ s2zero) {
  __shared__ float red[128];
  const int tid = threadIdx.x, rb = blockIdx.x;
  if (tid < 128) red[tid] = 0.f;
  if (rb == 0) {
    for (int t = 0; t < 16; ++t) s2zero[t * 256 + tid] = 0.f;
  }
  __syncthreads();
  for (int t = 0; t < 32; ++t) {
    const int task = t * 256 + tid;
    const int row = task & 127, kg = task >> 7;   // kg 0..63
    const float* src = x + (size_t)(rb * 128 + row) * ND + kg * 8;
    float4 v0 = *(const float4*)src;
    float4 v1 = *(const float4*)(src + 4);
    float ss = v0.x*v0.x + v0.y*v0.y + v0.z*v0.z + v0.w*v0.w
             + v1.x*v1.x + v1.y*v1.y + v1.z*v1.z + v1.w*v1.w;
    atomicAdd(&red[row], ss);
    uint4 pk;
    pk.x = (u32)f2bf(v0.x) | ((u32)f2bf(v0.y) << 16);
    pk.y = (u32)f2bf(v0.z) | ((u32)f2bf(v0.w) << 16);
    pk.z = (u32)f2bf(v1.x) | ((u32)f2bf(v1.y) << 16);
    pk.w = (u32)f2bf(v1.z) | ((u32)f2bf(v1.w) << 16);
    *(uint4*)&x_ws[((size_t)(rb * 64 + kg) * 128 + row) * 8] = pk;
  }
  __syncthreads();
  if (tid < 128) x2[rb * 128 + tid] = red[tid];
}

// ---------- prep: support -> bf16 swizzled [mb(32)][kg(64)][m(128)][8], s2 (atomic partials) ----------
__global__ __launch_bounds__(256) void prep_s(const float* __restrict__ s,
                                              u16* __restrict__ s_ws,
                                              float* __restrict__ s2) {
  __shared__ float red[128];
  const int tid = threadIdx.x;
  const int mb = blockIdx.x >> 2, ksl = blockIdx.x & 3;
  if (tid < 128) red[tid] = 0.f;
  __syncthreads();
  for (int t = 0; t < 8; ++t) {
    const int task = t * 256 + tid;
    const int m = task & 127, kgl = task >> 7;    // kgl 0..15
    const int kg = ksl * 16 + kgl;
    const float* src = s + (size_t)(mb * 128 + m) * ND + kg * 8;
    float4 v0 = *(const float4*)src;
    float4 v1 = *(const float4*)(src + 4);
    float ss = v0.x*v0.x + v0.y*v0.y + v0.z*v0.z + v0.w*v0.w
             + v1.x*v1.x + v1.y*v1.y + v1.z*v1.z + v1.w*v1.w;
    atomicAdd(&red[m], ss);
    uint4 pk;
    pk.x = (u32)f2bf(v0.x) | ((u32)f2bf(v0.y) << 16);
    pk.y = (u32)f2bf(v0.z) | ((u32)f2bf(v0.w) << 16);
    pk.z = (u32)f2bf(v1.x) | ((u32)f2bf(v1.y) << 16);
    pk.w = (u32)f2bf(v1.z) | ((u32)f2bf(v1.w) << 16);
    *(uint4*)&s_ws[((size_t)(mb * 64 + kg) * 128 + m) * 8] = pk;
  }
  __syncthreads();
  if (tid < 128) atomicAdd(&s2[mb * 128 + tid], red[tid]);
}

// ---------- prep: head_w -> bf16 swizzled [slab=(mb*16+kg)][o(128)][8] ----------
__global__ __launch_bounds__(256) void prep_hw(const float* __restrict__ hw,
                                               u16* __restrict__ hw_ws) {
  const int gt = blockIdx.x * 256 + threadIdx.x;  // 0..65535
  const int slab = gt >> 7, o = gt & 127;         // slab 0..511
  const int mb = slab >> 4, kg = slab & 15;
  const float* src = hw + (size_t)o * NM + mb * 128 + kg * 8;
  float4 v0 = *(const float4*)src;
  float4 v1 = *(const float4*)(src + 4);
  uint4 pk;
  pk.x = (u32)f2bf(v0.x) | ((u32)f2bf(v0.y) << 16);
  pk.y = (u32)f2bf(v0.z) | ((u32)f2bf(v0.w) << 16);
  pk.z = (u32)f2bf(v1.x) | ((u32)f2bf(v1.y) << 16);
  pk.w = (u32)f2bf(v1.z) | ((u32)f2bf(v1.w) << 16);
  *(uint4*)&hw_ws[((size_t)slab * 128 + o) * 8] = pk;
}

// ---------- main fused kernel ----------
// grid 512: rb = blockIdx>>2 (128 row-blocks of 128), half = blockIdx&3 (M split 4x)
// block 256 thr = 4 waves; wave tile 64x64 (4x4 16x16x32 mfma frags)
__global__ __launch_bounds__(256, 2)
void rbf_fused(const u16* __restrict__ x_ws, const u16* __restrict__ s_ws,
               const u16* __restrict__ hw_ws, const float* __restrict__ x2,
               const float* __restrict__ s2, const float* __restrict__ gamma_p,
               float* __restrict__ pout)
{
  __shared__ __align__(16) u16 Xs[2][4 * 128 * 8];   // 8 KB x2
  __shared__ __align__(16) u16 Ss[2][4 * 128 * 8];   // 8 KB x2
  __shared__ __align__(16) u16 Ks[16 * 128 * 8];     // 32 KB  (total 64 KB)

  const int tid  = threadIdx.x;
  const int w    = tid >> 6;
  const int lane = tid & 63;
  const int quad = lane >> 4;
  const int l16  = lane & 15;
  const int wr   = w & 1;    // wave row-half (rows wr*64..)
  const int wc   = w >> 1;   // wave col-half (cols wc*64..)
  const int rb   = blockIdx.x >> 2;
  const int half = blockIdx.x & 3;
  const int b0   = rb * 128;

  const float gamma = gamma_p[0];

  float x2v[4][4];
  #pragma unroll
  for (int r = 0; r < 4; ++r)
    #pragma unroll
    for (int i = 0; i < 4; ++i)
      x2v[r][i] = x2[b0 + wr * 64 + r * 16 + quad * 4 + i];

  const f32x4 zf = {0.f, 0.f, 0.f, 0.f};
  f32x4 acc_xs[4][4];
  f32x4 acc_out[4][4];
  #pragma unroll
  for (int r = 0; r < 4; ++r)
    #pragma unroll
    for (int c = 0; c < 4; ++c) { acc_xs[r][c] = zf; acc_out[r][c] = zf; }

  // stage chunk g (kc = g&15 covers k=kc*32..+31; buf = g&1). 16 slab-halves, 4 per wave.
  auto stage_chunk = [&](int g) {
    const int kc  = g & 15;
    const int mt  = g >> 4;
    const int buf = g & 1;
    const int mtg = half * 8 + mt;
    #pragma unroll
    for (int t = 0; t < 4; ++t) {
      const int i = (t << 2) | w;       // 0..15, wave-uniform
      if (i < 8) {                      // X slabs
        const int kgl = i >> 1, sub = i & 1;
        const int kgg = kc * 4 + kgl;
        const u16* src = x_ws + (((size_t)(rb * 64 + kgg)) * 128 + sub * 64 + lane) * 8;
        u16* dst = &Xs[buf][(kgl * 128 + sub * 64 + lane) * 8];
        stage16(src, dst);
      } else {                          // S slabs
        const int j = i - 8;
        const int kgl = j >> 1, sub = j & 1;
        const int kgg = kc * 4 + kgl;
        const u16* src = s_ws + (((size_t)(mtg * 64 + kgg)) * 128 + sub * 64 + lane) * 8;
        u16* dst = &Ss[buf][(kgl * 128 + sub * 64 + lane) * 8];
        stage16(src, dst);
      }
    }
  };

  auto compute_chunk = [&](int buf) {
    bf16x8 av[4], bv[4];
    #pragma unroll
    for (int r = 0; r < 4; ++r)
      av[r] = *(const bf16x8*)&Xs[buf][(quad * 128 + wr * 64 + r * 16 + l16) * 8];
    #pragma unroll
    for (int c = 0; c < 4; ++c)
      bv[c] = *(const bf16x8*)&Ss[buf][(quad * 128 + wc * 64 + c * 16 + l16) * 8];
    #pragma unroll
    for (int r = 0; r < 4; ++r)
      #pragma unroll
      for (int c = 0; c < 4; ++c)
        acc_xs[r][c] = __builtin_amdgcn_mfma_f32_16x16x32_bf16(av[r], bv[c], acc_xs[r][c], 0, 0, 0);
  };

  stage_chunk(0);
  __syncthreads();

  #pragma unroll 1
  for (int mt = 0; mt < 8; ++mt) {
    #pragma unroll 2
    for (int kc = 0; kc < 16; ++kc) {
      const int g = (mt << 4) | kc;
      if (g + 1 < 128) stage_chunk(g + 1);
      compute_chunk(g & 1);
      if (kc < 15) __syncthreads();
    }

    const int mtg = half * 8 + mt;
    // ---- exp epilogue: acc_xs -> k(bf16) into Ks (GEMM2 A-layout), reset acc_xs ----
    float s2v[4];
    #pragma unroll
    for (int c = 0; c < 4; ++c)
      s2v[c] = s2[mtg * 128 + wc * 64 + c * 16 + l16];
    #pragma unroll
    for (int r = 0; r < 4; ++r)
      #pragma unroll
      for (int c = 0; c < 4; ++c) {
        const int mcol = wc * 64 + c * 16 + l16;
        const int kg = mcol >> 3, e = mcol & 7;
        #pragma unroll
        for (int i = 0; i < 4; ++i) {
          float sq = x2v[r][i] + s2v[c] - 2.0f * acc_xs[r][c][i];
          sq = fmaxf(sq, 0.0f);
          const float kv = __expf(-gamma * sq);
          Ks[(kg * 128 + wr * 64 + r * 16 + quad * 4 + i) * 8 + e] = f2bf(kv);
          acc_xs[r][c][i] = 0.0f;
        }
      }
    __syncthreads();

    // ---- GEMM2: acc_out += K(128x128) * head_w(o,m)^T ; B-frags straight from L2 ----
    #pragma unroll
    for (int ks = 0; ks < 4; ++ks) {
      const int kg = ks * 4 + quad;
      bf16x8 a2[4], b2[4];
      #pragma unroll
      for (int r = 0; r < 4; ++r)
        a2[r] = *(const bf16x8*)&Ks[(kg * 128 + wr * 64 + r * 16 + l16) * 8];
      #pragma unroll
      for (int c = 0; c < 4; ++c)
        b2[c] = *(const bf16x8*)(hw_ws + (((size_t)(mtg * 16 + kg)) * 128 + wc * 64 + c * 16 + l16) * 8);
      #pragma unroll
      for (int r = 0; r < 4; ++r)
        #pragma unroll
        for (int c = 0; c < 4; ++c)
          acc_out[r][c] = __builtin_amdgcn_mfma_f32_16x16x32_bf16(a2[r], b2[c], acc_out[r][c], 0, 0, 0);
    }
  }

  // ---- write partial out ----
  #pragma unroll
  for (int r = 0; r < 4; ++r)
    #pragma unroll
    for (int c = 0; c < 4; ++c)
      #pragma unroll
      for (int i = 0; i < 4; ++i) {
        const int row = b0 + wr * 64 + r * 16 + quad * 4 + i;
        const int col = wc * 64 + c * 16 + l16;
        pout[(size_t)half * ((size_t)NB * NOUT) + (size_t)row * NOUT + col] = acc_out[r][c][i];
      }
}

// ---------- reduce partials + bias + affine ----------
__global__ __launch_bounds__(256) void reduce_out(const float* __restrict__ pout,
                                                  const float* __restrict__ head_b,
                                                  const float* __restrict__ scale_p,
                                                  const float* __restrict__ shift_p,
                                                  float* __restrict__ out) {
  const int gt = blockIdx.x * 256 + threadIdx.x;  // x4 floats
  const float scl = scale_p[0], shf = shift_p[0];
  const size_t P = (size_t)NB * NOUT;
  float4 a = *(const float4*)(pout + (size_t)gt * 4);
  float4 b = *(const float4*)(pout + P + (size_t)gt * 4);
  float4 c = *(const float4*)(pout + 2 * P + (size_t)gt * 4);
  float4 d = *(const float4*)(pout + 3 * P + (size_t)gt * 4);
  float4 hb = *(const float4*)(head_b + ((gt & 31) * 4));
  float4 o;
  o.x = scl * (a.x + b.x + c.x + d.x + hb.x) + shf;
  o.y = scl * (a.y + b.y + c.y + d.y + hb.y) + shf;
  o.z = scl * (a.z + b.z + c.z + d.z + hb.z) + shf;
  o.w = scl * (a.w + b.w + c.w + d.w + hb.w) + shf;
  *(float4*)(out + (size_t)gt * 4) = o;
}

// ---------- launch ----------
extern "C" void kernel_launch(void* const* d_in, const int* in_sizes, int n_in,
                              void* d_out, int out_size, void* d_ws, size_t ws_size,
                              hipStream_t stream) {
  const float* x       = (const float*)d_in[0];
  const float* support = (const float*)d_in[1];
  const float* gamma   = (const float*)d_in[2];
  const float* head_w  = (const float*)d_in[3];
  const float* head_b  = (const float*)d_in[4];
  const float* scale   = (const float*)d_in[5];
  const float* shift   = (const float*)d_in[6];
  float* out = (float*)d_out;

  char* w = (char*)d_ws;
  u16*   x_ws  = (u16*)(w);                       // 16,777,216 B
  u16*   s_ws  = (u16*)(w + 16777216);            //  4,194,304 B
  u16*   hw_ws = (u16*)(w + 20971520);            //  1,048,576 B
  float* x2    = (float*)(w + 22020096);          //     65,536 B
  float* s2    = (float*)(w + 22085632);          //     16,384 B
  float* pout  = (float*)(w + 22102016);          // 33,554,432 B  (total ~53.1 MB)

  prep_x <<<128, 256, 0, stream>>>(x, x_ws, x2, s2);
  prep_s <<<128, 256, 0, stream>>>(support, s_ws, s2);
  prep_hw<<<256, 256, 0, stream>>>(head_w, hw_ws);
  rbf_fused<<<512, 256, 0, stream>>>(x_ws, s_ws, hw_ws, x2, s2, gamma, pout);
  reduce_out<<<2048, 256, 0, stream>>>(pout, head_b, scale, shift, out);
}